// Round 6
// baseline (545.267 us; speedup 1.0000x reference)
//
#include <hip/hip_runtime.h>
#include <hip/hip_bf16.h>

#define NN 100000
#define EE 1600000
#define DD 128

#define BSH 9                       // 512 nodes per bucket
#define NBUK ((NN + 511) / 512)     // 196
#define EPB 8192                    // edges per block in partition kernels
#define AST 136                     // LDS row stride (halves): 272B, 16B-aligned, 2-way banks

typedef __attribute__((ext_vector_type(8))) _Float16 half8;
typedef __attribute__((ext_vector_type(2))) _Float16 half2v;
typedef __attribute__((ext_vector_type(4))) float f32x4;

// ---------------- dtype detection (int32 vs int64 edge_index) ----------------
__global__ void k_detect(const long long* __restrict__ ei64, int* __restrict__ flag) {
    __shared__ int ok;
    if (threadIdx.x == 0) ok = 1;
    __syncthreads();
    long long v = ei64[threadIdx.x];
    if (v < 0 || v >= (long long)NN) atomicAnd(&ok, 0);
    __syncthreads();
    if (threadIdx.x == 0) *flag = ok;  // 1 => int64 layout, 0 => int32
}

__device__ inline int load_edge(const int* ei32, const long long* ei64, int is64, size_t pos) {
    return is64 ? (int)ei64[pos] : ei32[pos];
}

// ---------------- bucket histogram (196 buckets of 512 dst nodes) ----------------
__global__ __launch_bounds__(1024) void k_bhist(const int* __restrict__ ei32,
                                                const long long* __restrict__ ei64,
                                                const int* __restrict__ flag,
                                                int* __restrict__ bcnt) {
    __shared__ int h[NBUK];
    int t = threadIdx.x;
    if (t < NBUK) h[t] = 0;
    __syncthreads();
    int is64 = *flag;
    int base = blockIdx.x * EPB;
    int end = min(base + EPB, EE);
    for (int e = base + t; e < end; e += 1024) {
        int d = load_edge(ei32, ei64, is64, (size_t)EE + e);
        atomicAdd(&h[d >> BSH], 1);
    }
    __syncthreads();
    if (t < NBUK && h[t] > 0) atomicAdd(&bcnt[t], h[t]);
}

__global__ __launch_bounds__(256) void k_bscan(const int* __restrict__ bcnt,
                                               int* __restrict__ bbase,
                                               int* __restrict__ bcur) {
    __shared__ int sm[256];
    int t = threadIdx.x;
    int v = (t < NBUK) ? bcnt[t] : 0;
    sm[t] = v;
    __syncthreads();
    for (int off = 1; off < 256; off <<= 1) {
        int u = (t >= off) ? sm[t - off] : 0;
        __syncthreads();
        sm[t] += u;
        __syncthreads();
    }
    if (t < NBUK) {
        int b = sm[t] - v;
        bbase[t] = b;
        bcur[t] = b;
    }
    if (t == 0) bbase[NBUK] = EE;
}

// ---------------- partition edges into bucket-contiguous staging ----------------
// two-pass (reload edges) to avoid dynamically-indexed per-thread arrays
__global__ __launch_bounds__(1024) void k_part(const int* __restrict__ ei32,
                                               const long long* __restrict__ ei64,
                                               const int* __restrict__ flag,
                                               int* __restrict__ bcur,
                                               unsigned* __restrict__ eb) {
    __shared__ int h[NBUK];
    __shared__ int cbase[NBUK];
    int t = threadIdx.x;
    if (t < NBUK) h[t] = 0;
    __syncthreads();
    int is64 = *flag;
    int base = blockIdx.x * EPB;
    int end = min(base + EPB, EE);
    for (int e = base + t; e < end; e += 1024) {
        int d = load_edge(ei32, ei64, is64, (size_t)EE + e);
        atomicAdd(&h[d >> BSH], 1);
    }
    __syncthreads();
    if (t < NBUK && h[t] > 0) cbase[t] = atomicAdd(&bcur[t], h[t]);
    __syncthreads();
    if (t < NBUK) h[t] = 0;   // reuse as local cursor
    __syncthreads();
    for (int e = base + t; e < end; e += 1024) {
        int s = load_edge(ei32, ei64, is64, (size_t)e);
        int d = load_edge(ei32, ei64, is64, (size_t)EE + e);
        int b = d >> BSH;
        int slot = atomicAdd(&h[b], 1);
        eb[cbase[b] + slot] = (unsigned)s | ((unsigned)(d & 511) << 17);
    }
}

// ---------------- per-bucket counting sort: one block per bucket ----------------
__global__ __launch_bounds__(1024) void k_bucket(const unsigned* __restrict__ eb,
                                                 const int* __restrict__ bbase,
                                                 int* __restrict__ rp,
                                                 int* __restrict__ ssrc) {
    __shared__ int ncnt[512];
    __shared__ int cur[512];
    int b = blockIdx.x, t = threadIdx.x;
    int ebeg = bbase[b], eend = bbase[b + 1];
    int nodeBase = b << BSH;
    int nNodes = min(512, NN - nodeBase);
    if (t < 512) ncnt[t] = 0;
    __syncthreads();
    for (int i = ebeg + t; i < eend; i += 1024) {
        unsigned v = eb[i];
        atomicAdd(&ncnt[v >> 17], 1);
    }
    __syncthreads();
    int own = (t < 512) ? ncnt[t] : 0;
    for (int off = 1; off < 512; off <<= 1) {
        int u = (t >= off && t < 512) ? ncnt[t - off] : 0;
        __syncthreads();
        if (t < 512) ncnt[t] += u;
        __syncthreads();
    }
    if (t < 512) {
        int excl = ncnt[t] - own;
        cur[t] = ebeg + excl;
        if (t < nNodes) rp[nodeBase + t] = ebeg + excl;
    }
    __syncthreads();
    for (int i = ebeg + t; i < eend; i += 1024) {
        unsigned v = eb[i];
        int slot = atomicAdd(&cur[v >> 17], 1);
        ssrc[slot] = (int)(v & 0x1FFFFu);
    }
    if (b == 0 && t == 0) rp[NN] = EE;
}

// ---------------- weight prep: f32 -> fp16 ----------------
__global__ void k_prepw(const float* __restrict__ w0, const float* __restrict__ w1,
                        const float* __restrict__ w2, const float* __restrict__ w3,
                        const float* __restrict__ w4, const float* __restrict__ w5,
                        _Float16* __restrict__ whi) {
    int i = blockIdx.x * 256 + threadIdx.x;     // 6 * 16384
    if (i >= 6 * 16384) return;
    int slot = i >> 14, idx = i & 16383;
    const float* w = slot == 0 ? w0 : slot == 1 ? w1 : slot == 2 ? w2
                   : slot == 3 ? w3 : slot == 4 ? w4 : w5;
    whi[i] = (_Float16)w[idx];
}

// ---------------- GEMM1: hH = relu(x@W1.T + b1), f32 A via f16 hi/lo ----------------
__global__ __launch_bounds__(256) void k_gemm1(const float* __restrict__ A,
                                               const _Float16* __restrict__ Wg,
                                               const float* __restrict__ bias,
                                               _Float16* __restrict__ out) {
    __shared__ _Float16 sW[128 * AST];
    int t = threadIdx.x;
    int wave = t >> 6, lane = t & 63;
    int lr = lane & 15, lk = lane >> 4;
    int rowBase = blockIdx.x * 128 + wave * 32;

    f32x4 acc[2][8];
#pragma unroll
    for (int mt = 0; mt < 2; ++mt)
#pragma unroll
        for (int nt = 0; nt < 8; ++nt) acc[mt][nt] = (f32x4){0.f, 0.f, 0.f, 0.f};

#pragma unroll
    for (int i = 0; i < 8; ++i) {
        int c = t + i * 256;
        int n = c >> 4, j = c & 15;
        *(half8*)(sW + n * AST + j * 8) = *(const half8*)(Wg + n * 128 + j * 8);
    }
    __syncthreads();

#pragma unroll
    for (int ks = 0; ks < 4; ++ks) {
        int kf = ks * 32 + lk * 8;
        half8 b[8];
#pragma unroll
        for (int nt = 0; nt < 8; ++nt)
            b[nt] = *(const half8*)(sW + (nt * 16 + lr) * AST + kf);
#pragma unroll
        for (int mt = 0; mt < 2; ++mt) {
            int row = rowBase + mt * 16 + lr;
            int rc = row < NN ? row : NN - 1;
            const float* ap = A + (size_t)rc * 128 + kf;
            float4 a0 = *(const float4*)ap;
            float4 a1 = *(const float4*)(ap + 4);
            float av[8] = {a0.x, a0.y, a0.z, a0.w, a1.x, a1.y, a1.z, a1.w};
            half8 ah, al;
#pragma unroll
            for (int j = 0; j < 8; ++j) {
                _Float16 h = (_Float16)av[j];
                ah[j] = h;
                al[j] = (_Float16)(av[j] - (float)h);
            }
#pragma unroll
            for (int nt = 0; nt < 8; ++nt) {
                acc[mt][nt] = __builtin_amdgcn_mfma_f32_16x16x32_f16(ah, b[nt], acc[mt][nt], 0, 0, 0);
                acc[mt][nt] = __builtin_amdgcn_mfma_f32_16x16x32_f16(al, b[nt], acc[mt][nt], 0, 0, 0);
            }
        }
    }

#pragma unroll
    for (int mt = 0; mt < 2; ++mt)
#pragma unroll
        for (int nt = 0; nt < 8; ++nt) {
            int col = nt * 16 + lr;
            float bia = bias[col];
#pragma unroll
            for (int r = 0; r < 4; ++r) {
                int row = rowBase + mt * 16 + lk * 4 + r;
                if (row < NN) {
                    float v = acc[mt][nt][r] + bia;
                    out[(size_t)row * 128 + col] = (_Float16)(v > 0.f ? v : 0.f);
                }
            }
        }
}

// ---------------- fused conv (+ optional linear): one block = 128 dst rows ----------------
// phase A: each wave aggregates its 32 mean-rows (gather) into LDS A-tile.
// pass 1: mean @ Wl.T (A from LDS). pass 2: + h_root @ Wr.T (A streamed from global).
// +bias, relu -> h2. If HASL: h2 -> LDS tile -> relu(h2@Wlin.T+blin). Output fp16 or f32.
template <bool HASL, bool OF16>
__global__ __launch_bounds__(256, 2) void k_conv(const _Float16* __restrict__ hsrc,
                                                 const int* __restrict__ rp,
                                                 const int* __restrict__ ssrc,
                                                 const _Float16* __restrict__ Wlg,
                                                 const _Float16* __restrict__ Wrg,
                                                 const float* __restrict__ bconv,
                                                 const _Float16* __restrict__ Wling,
                                                 const float* __restrict__ blin,
                                                 void* __restrict__ out) {
    __shared__ _Float16 sW[128 * AST];
    __shared__ _Float16 sA[128 * AST];
    int t = threadIdx.x;
    int wave = t >> 6, lane = t & 63;
    int lr = lane & 15, lk = lane >> 4;
    int rowBase = blockIdx.x * 128 + wave * 32;
    const half2v* hp = (const half2v*)hsrc;

    // ---- phase A: aggregate means into own 32 LDS rows ----
    for (int i = 0; i < 32; ++i) {
        int node = rowBase + i;
        float ax = 0.f, ay = 0.f;
        int deg = 0;
        if (node < NN) {
            int s = __builtin_amdgcn_readfirstlane(rp[node]);
            int e = __builtin_amdgcn_readfirstlane(rp[node + 1]);
            deg = e - s;
            int j = s;
            for (; j + 8 <= e; j += 8) {
                int i0 = ssrc[j], i1 = ssrc[j + 1], i2 = ssrc[j + 2], i3 = ssrc[j + 3];
                int i4 = ssrc[j + 4], i5 = ssrc[j + 5], i6 = ssrc[j + 6], i7 = ssrc[j + 7];
                half2v v0 = hp[(size_t)i0 * 64 + lane];
                half2v v1 = hp[(size_t)i1 * 64 + lane];
                half2v v2 = hp[(size_t)i2 * 64 + lane];
                half2v v3 = hp[(size_t)i3 * 64 + lane];
                half2v v4 = hp[(size_t)i4 * 64 + lane];
                half2v v5 = hp[(size_t)i5 * 64 + lane];
                half2v v6 = hp[(size_t)i6 * 64 + lane];
                half2v v7 = hp[(size_t)i7 * 64 + lane];
                ax += ((float)v0.x + (float)v1.x) + ((float)v2.x + (float)v3.x)
                    + ((float)v4.x + (float)v5.x) + ((float)v6.x + (float)v7.x);
                ay += ((float)v0.y + (float)v1.y) + ((float)v2.y + (float)v3.y)
                    + ((float)v4.y + (float)v5.y) + ((float)v6.y + (float)v7.y);
            }
            for (; j < e; ++j) {
                half2v v0 = hp[(size_t)ssrc[j] * 64 + lane];
                ax += (float)v0.x;
                ay += (float)v0.y;
            }
        }
        float inv = deg > 0 ? 1.0f / (float)deg : 0.f;
        half2v o;
        o.x = (_Float16)(ax * inv);
        o.y = (_Float16)(ay * inv);
        *(half2v*)(sA + (wave * 32 + i) * AST + 2 * lane) = o;
    }
    __syncthreads();

    // ---- stage Wl ----
#pragma unroll
    for (int i = 0; i < 8; ++i) {
        int c = t + i * 256;
        int n = c >> 4, j = c & 15;
        *(half8*)(sW + n * AST + j * 8) = *(const half8*)(Wlg + n * 128 + j * 8);
    }
    __syncthreads();

    f32x4 acc[2][8];
#pragma unroll
    for (int mt = 0; mt < 2; ++mt)
#pragma unroll
        for (int nt = 0; nt < 8; ++nt) acc[mt][nt] = (f32x4){0.f, 0.f, 0.f, 0.f};

    // ---- pass 1: mean (LDS) @ Wl ----
#pragma unroll
    for (int ks = 0; ks < 4; ++ks) {
        int kf = ks * 32 + lk * 8;
        half8 b[8];
#pragma unroll
        for (int nt = 0; nt < 8; ++nt)
            b[nt] = *(const half8*)(sW + (nt * 16 + lr) * AST + kf);
#pragma unroll
        for (int mt = 0; mt < 2; ++mt) {
            half8 a = *(const half8*)(sA + (wave * 32 + mt * 16 + lr) * AST + kf);
#pragma unroll
            for (int nt = 0; nt < 8; ++nt)
                acc[mt][nt] = __builtin_amdgcn_mfma_f32_16x16x32_f16(a, b[nt], acc[mt][nt], 0, 0, 0);
        }
    }
    __syncthreads();

    // ---- stage Wr ----
#pragma unroll
    for (int i = 0; i < 8; ++i) {
        int c = t + i * 256;
        int n = c >> 4, j = c & 15;
        *(half8*)(sW + n * AST + j * 8) = *(const half8*)(Wrg + n * 128 + j * 8);
    }
    __syncthreads();

    // ---- pass 2: h_root (global) @ Wr ----
#pragma unroll
    for (int ks = 0; ks < 4; ++ks) {
        int kf = ks * 32 + lk * 8;
        half8 b[8];
#pragma unroll
        for (int nt = 0; nt < 8; ++nt)
            b[nt] = *(const half8*)(sW + (nt * 16 + lr) * AST + kf);
#pragma unroll
        for (int mt = 0; mt < 2; ++mt) {
            int row = rowBase + mt * 16 + lr;
            int rc = row < NN ? row : NN - 1;
            half8 a = *(const half8*)(hsrc + (size_t)rc * 128 + kf);
#pragma unroll
            for (int nt = 0; nt < 8; ++nt)
                acc[mt][nt] = __builtin_amdgcn_mfma_f32_16x16x32_f16(a, b[nt], acc[mt][nt], 0, 0, 0);
        }
    }

    if (!HASL) {
        // epilogue: bias + relu, store
#pragma unroll
        for (int mt = 0; mt < 2; ++mt)
#pragma unroll
            for (int nt = 0; nt < 8; ++nt) {
                int col = nt * 16 + lr;
                float bia = bconv[col];
#pragma unroll
                for (int r = 0; r < 4; ++r) {
                    int row = rowBase + mt * 16 + lk * 4 + r;
                    if (row < NN) {
                        float v = acc[mt][nt][r] + bia;
                        v = v > 0.f ? v : 0.f;
                        if (OF16) ((_Float16*)out)[(size_t)row * 128 + col] = (_Float16)v;
                        else ((float*)out)[(size_t)row * 128 + col] = v;
                    }
                }
            }
        return;
    }

    // ---- h2 = relu(conv + bias) -> own LDS rows (C layout scatter) ----
#pragma unroll
    for (int mt = 0; mt < 2; ++mt)
#pragma unroll
        for (int nt = 0; nt < 8; ++nt) {
            int col = nt * 16 + lr;
            float bia = bconv[col];
#pragma unroll
            for (int r = 0; r < 4; ++r) {
                float v = acc[mt][nt][r] + bia;
                sA[(wave * 32 + mt * 16 + lk * 4 + r) * AST + col] = (_Float16)(v > 0.f ? v : 0.f);
            }
        }
    __syncthreads();

    // ---- stage Wlin ----
#pragma unroll
    for (int i = 0; i < 8; ++i) {
        int c = t + i * 256;
        int n = c >> 4, j = c & 15;
        *(half8*)(sW + n * AST + j * 8) = *(const half8*)(Wling + n * 128 + j * 8);
    }
    __syncthreads();

#pragma unroll
    for (int mt = 0; mt < 2; ++mt)
#pragma unroll
        for (int nt = 0; nt < 8; ++nt) acc[mt][nt] = (f32x4){0.f, 0.f, 0.f, 0.f};

    // ---- pass 3: h2 (LDS) @ Wlin ----
#pragma unroll
    for (int ks = 0; ks < 4; ++ks) {
        int kf = ks * 32 + lk * 8;
        half8 b[8];
#pragma unroll
        for (int nt = 0; nt < 8; ++nt)
            b[nt] = *(const half8*)(sW + (nt * 16 + lr) * AST + kf);
#pragma unroll
        for (int mt = 0; mt < 2; ++mt) {
            half8 a = *(const half8*)(sA + (wave * 32 + mt * 16 + lr) * AST + kf);
#pragma unroll
            for (int nt = 0; nt < 8; ++nt)
                acc[mt][nt] = __builtin_amdgcn_mfma_f32_16x16x32_f16(a, b[nt], acc[mt][nt], 0, 0, 0);
        }
    }

#pragma unroll
    for (int mt = 0; mt < 2; ++mt)
#pragma unroll
        for (int nt = 0; nt < 8; ++nt) {
            int col = nt * 16 + lr;
            float bia = blin[col];
#pragma unroll
            for (int r = 0; r < 4; ++r) {
                int row = rowBase + mt * 16 + lk * 4 + r;
                if (row < NN) {
                    float v = acc[mt][nt][r] + bia;
                    v = v > 0.f ? v : 0.f;
                    if (OF16) ((_Float16*)out)[(size_t)row * 128 + col] = (_Float16)v;
                    else ((float*)out)[(size_t)row * 128 + col] = v;
                }
            }
        }
}

// ---------------- launch ----------------
extern "C" void kernel_launch(void* const* d_in, const int* in_sizes, int n_in,
                              void* d_out, int out_size, void* d_ws, size_t ws_size,
                              hipStream_t stream) {
    const float* x = (const float*)d_in[0];
    const int* ei32 = (const int*)d_in[1];
    const long long* ei64 = (const long long*)d_in[1];
    const float* b1 = (const float*)d_in[3];
    const float* b2 = (const float*)d_in[5];
    const float* c1_bl = (const float*)d_in[7];
    const float* c2_bl = (const float*)d_in[10];

    char* ws = (char*)d_ws;
    const size_t H16 = (size_t)NN * 128 * 2;     // 25,600,000
    _Float16* hH = (_Float16*)ws;                // h1 table
    _Float16* h3H = (_Float16*)(ws + H16);       // h3 table
    int* ssrc = (int*)(ws + 2 * H16);            // E ints
    int* rp = (int*)(ws + 2 * H16 + 6400000);    // N+1 (padded 400128)
    int* bufs = (int*)(ws + 2 * H16 + 6400000 + 400128);
    _Float16* whi = (_Float16*)(ws + 2 * H16 + 6400000 + 2 * 400128);
    int* flag = (int*)((char*)(whi + 6 * 16384));

    int* bcnt = bufs;                // NBUK
    int* bbase = bufs + 256;         // NBUK+1
    int* bcur = bufs + 512;          // NBUK
    unsigned* eb = (unsigned*)hH;    // E staged edges (hH written only later)

    k_detect<<<1, 256, 0, stream>>>(ei64, flag);
    hipMemsetAsync(bcnt, 0, NBUK * 4, stream);
    int pgrid = (EE + EPB - 1) / EPB;   // 196
    k_bhist<<<pgrid, 1024, 0, stream>>>(ei32, ei64, flag, bcnt);
    k_bscan<<<1, 256, 0, stream>>>(bcnt, bbase, bcur);
    k_part<<<pgrid, 1024, 0, stream>>>(ei32, ei64, flag, bcur, eb);
    k_bucket<<<NBUK, 1024, 0, stream>>>(eb, bbase, rp, ssrc);
    k_prepw<<<(6 * 16384 + 255) / 256, 256, 0, stream>>>(
        (const float*)d_in[2], (const float*)d_in[6], (const float*)d_in[8],
        (const float*)d_in[4], (const float*)d_in[9], (const float*)d_in[11], whi);

    dim3 g((NN + 127) / 128);
    // h1 = relu(x@W1.T+b1) -> fp16 hH
    k_gemm1<<<g, 256, 0, stream>>>(x, whi + 0 * 16384, b1, hH);
    // fused conv1 + lin2: h3 = relu(relu(sage1(h1))@W2.T+b2) -> h3H
    k_conv<true, true><<<g, 256, 0, stream>>>(
        hH, rp, ssrc, whi + 1 * 16384, whi + 2 * 16384, c1_bl,
        whi + 3 * 16384, b2, h3H);
    // fused conv2 -> f32 d_out
    k_conv<false, false><<<g, 256, 0, stream>>>(
        h3H, rp, ssrc, whi + 4 * 16384, whi + 5 * 16384, c2_bl,
        nullptr, nullptr, d_out);
}

// Round 7
// 391.273 us; speedup vs baseline: 1.3936x; 1.3936x over previous
//
#include <hip/hip_runtime.h>
#include <hip/hip_bf16.h>

#define NN 100000
#define EE 1600000
#define DD 128

#define BSH 9                       // 512 nodes per bucket
#define NBUK ((NN + 511) / 512)     // 196
#define EPB 8192                    // edges per block in partition kernels

typedef __attribute__((ext_vector_type(8))) _Float16 half8;
typedef __attribute__((ext_vector_type(2))) _Float16 half2v;
typedef __attribute__((ext_vector_type(4))) float f32x4;

// ---------------- dtype detection (int32 vs int64 edge_index) ----------------
__global__ void k_detect(const long long* __restrict__ ei64, int* __restrict__ flag) {
    __shared__ int ok;
    if (threadIdx.x == 0) ok = 1;
    __syncthreads();
    long long v = ei64[threadIdx.x];   // 256 samples; safe either way (2E elems)
    if (v < 0 || v >= (long long)NN) atomicAnd(&ok, 0);
    __syncthreads();
    if (threadIdx.x == 0) *flag = ok;  // 1 => int64 layout, 0 => int32
}

__device__ inline int load_edge(const int* ei32, const long long* ei64, int is64, size_t pos) {
    return is64 ? (int)ei64[pos] : ei32[pos];
}

// ---------------- bucket histogram (196 buckets of 512 dst nodes) ----------------
__global__ __launch_bounds__(1024) void k_bhist(const int* __restrict__ ei32,
                                                const long long* __restrict__ ei64,
                                                const int* __restrict__ flag,
                                                int* __restrict__ bcnt) {
    __shared__ int h[NBUK];
    int t = threadIdx.x;
    if (t < NBUK) h[t] = 0;
    __syncthreads();
    int is64 = *flag;
    int base = blockIdx.x * EPB;
    int end = min(base + EPB, EE);
    for (int e = base + t; e < end; e += 1024) {
        int d = load_edge(ei32, ei64, is64, (size_t)EE + e);
        atomicAdd(&h[d >> BSH], 1);
    }
    __syncthreads();
    if (t < NBUK && h[t] > 0) atomicAdd(&bcnt[t], h[t]);
}

__global__ __launch_bounds__(256) void k_bscan(const int* __restrict__ bcnt,
                                               int* __restrict__ bbase,
                                               int* __restrict__ bcur) {
    __shared__ int sm[256];
    int t = threadIdx.x;
    int v = (t < NBUK) ? bcnt[t] : 0;
    sm[t] = v;
    __syncthreads();
    for (int off = 1; off < 256; off <<= 1) {
        int u = (t >= off) ? sm[t - off] : 0;
        __syncthreads();
        sm[t] += u;
        __syncthreads();
    }
    if (t < NBUK) {
        int b = sm[t] - v;
        bbase[t] = b;
        bcur[t] = b;
    }
    if (t == 0) bbase[NBUK] = EE;
}

// ---------------- partition edges into bucket-contiguous staging ----------------
// staged value: src (17 bits) | dstLocal (9 bits) << 17
__global__ __launch_bounds__(1024) void k_part(const int* __restrict__ ei32,
                                               const long long* __restrict__ ei64,
                                               const int* __restrict__ flag,
                                               int* __restrict__ bcur,
                                               unsigned* __restrict__ eb) {
    __shared__ int h[NBUK];
    __shared__ int cbase[NBUK];
    int t = threadIdx.x;
    if (t < NBUK) h[t] = 0;
    __syncthreads();
    int is64 = *flag;
    int base = blockIdx.x * EPB;
    int end = min(base + EPB, EE);
    int mys[8], myd[8];
    int cnt_i = 0;
    for (int e = base + t; e < end; e += 1024) {
        int s = load_edge(ei32, ei64, is64, (size_t)e);
        int d = load_edge(ei32, ei64, is64, (size_t)EE + e);
        mys[cnt_i] = s;
        myd[cnt_i] = d;
        ++cnt_i;
        atomicAdd(&h[d >> BSH], 1);
    }
    __syncthreads();
    if (t < NBUK && h[t] > 0) cbase[t] = atomicAdd(&bcur[t], h[t]);
    __syncthreads();
    if (t < NBUK) h[t] = 0;   // reuse as local cursor
    __syncthreads();
    for (int i = 0; i < cnt_i; ++i) {
        int b = myd[i] >> BSH;
        int slot = atomicAdd(&h[b], 1);
        unsigned v = (unsigned)mys[i] | ((unsigned)(myd[i] & 511) << 17);
        eb[cbase[b] + slot] = v;
    }
}

// ---------------- per-bucket counting sort: one block per bucket ----------------
__global__ __launch_bounds__(1024) void k_bucket(const unsigned* __restrict__ eb,
                                                 const int* __restrict__ bbase,
                                                 int* __restrict__ rp,
                                                 int* __restrict__ ssrc) {
    __shared__ int ncnt[512];
    __shared__ int cur[512];
    int b = blockIdx.x, t = threadIdx.x;
    int ebeg = bbase[b], eend = bbase[b + 1];
    int nodeBase = b << BSH;
    int nNodes = min(512, NN - nodeBase);
    if (t < 512) ncnt[t] = 0;
    __syncthreads();
    for (int i = ebeg + t; i < eend; i += 1024) {
        unsigned v = eb[i];
        atomicAdd(&ncnt[v >> 17], 1);
    }
    __syncthreads();
    int own = (t < 512) ? ncnt[t] : 0;
    for (int off = 1; off < 512; off <<= 1) {
        int u = (t >= off && t < 512) ? ncnt[t - off] : 0;
        __syncthreads();
        if (t < 512) ncnt[t] += u;
        __syncthreads();
    }
    if (t < 512) {
        int excl = ncnt[t] - own;
        cur[t] = ebeg + excl;
        if (t < nNodes) rp[nodeBase + t] = ebeg + excl;
    }
    __syncthreads();
    for (int i = ebeg + t; i < eend; i += 1024) {
        unsigned v = eb[i];
        int slot = atomicAdd(&cur[v >> 17], 1);
        ssrc[slot] = (int)(v & 0x1FFFFu);
    }
    if (b == 0 && t == 0) rp[NN] = EE;
}

// ---------------- weight prep: f32 -> fp16 (single precision level) ----------------
__global__ void k_prepw(const float* __restrict__ w0, const float* __restrict__ w1,
                        const float* __restrict__ w2, const float* __restrict__ w3,
                        const float* __restrict__ w4, const float* __restrict__ w5,
                        _Float16* __restrict__ whi) {
    int i = blockIdx.x * 256 + threadIdx.x;     // 6 * 16384
    if (i >= 6 * 16384) return;
    int slot = i >> 14, idx = i & 16383;
    const float* w = slot == 0 ? w0 : slot == 1 ? w1 : slot == 2 ? w2
                   : slot == 3 ? w3 : slot == 4 ? w4 : w5;
    whi[i] = (_Float16)w[idx];
}

// ---------------- GEMM: out = relu(A@W1.T [+ A2@W2.T] + bias) ----------------
// W staged in LDS (row stride 136 fp16 = 272B: 16B-aligned b128 reads, 2-way banks).
// fp16 A: 1 MFMA/tile. f32 A: f16 hi/lo split of A, 2 MFMAs/tile.
#define WSTR 136

template <bool DUAL, bool AF16, bool OF16>
__global__ __launch_bounds__(256) void k_gemm(const void* __restrict__ A,
                                              const _Float16* __restrict__ W1g,
                                              const void* __restrict__ A2,
                                              const _Float16* __restrict__ W2g,
                                              const float* __restrict__ bias,
                                              void* __restrict__ out) {
    __shared__ _Float16 sW[128 * WSTR];
    int t = threadIdx.x;
    int wave = t >> 6;
    int lane = t & 63;
    int lr = lane & 15;
    int lk = lane >> 4;
    int rowBase = blockIdx.x * 128 + wave * 32;

    f32x4 acc[2][8];
#pragma unroll
    for (int mt = 0; mt < 2; ++mt)
#pragma unroll
        for (int nt = 0; nt < 8; ++nt) acc[mt][nt] = (f32x4){0.f, 0.f, 0.f, 0.f};

    const int NPASS = DUAL ? 2 : 1;
    for (int pass = 0; pass < NPASS; ++pass) {
        const _Float16* Wg = pass ? W2g : W1g;
        const void* Ap = pass ? A2 : A;
        if (pass) __syncthreads();             // protect LDS before overwrite
        // stage weights: 2048 16B chunks, 8 per thread, coalesced
#pragma unroll
        for (int i = 0; i < 8; ++i) {
            int c = t + i * 256;
            int n = c >> 4, j = c & 15;
            *(half8*)(sW + n * WSTR + j * 8) = *(const half8*)(Wg + n * 128 + j * 8);
        }
        __syncthreads();

#pragma unroll
        for (int ks = 0; ks < 4; ++ks) {
            int kf = ks * 32 + lk * 8;
            half8 b[8];
#pragma unroll
            for (int nt = 0; nt < 8; ++nt)
                b[nt] = *(const half8*)(sW + (nt * 16 + lr) * WSTR + (ks * 4 + lk) * 8);
#pragma unroll
            for (int mt = 0; mt < 2; ++mt) {
                int row = rowBase + mt * 16 + lr;
                int rc = row < NN ? row : NN - 1;
                if (AF16) {
                    half8 a = *(const half8*)((const _Float16*)Ap + (size_t)rc * 128 + kf);
#pragma unroll
                    for (int nt = 0; nt < 8; ++nt)
                        acc[mt][nt] = __builtin_amdgcn_mfma_f32_16x16x32_f16(a, b[nt], acc[mt][nt], 0, 0, 0);
                } else {
                    const float* ap = (const float*)Ap + (size_t)rc * 128 + kf;
                    float4 a0 = *(const float4*)ap;
                    float4 a1 = *(const float4*)(ap + 4);
                    float av[8] = {a0.x, a0.y, a0.z, a0.w, a1.x, a1.y, a1.z, a1.w};
                    half8 ah, al;
#pragma unroll
                    for (int j = 0; j < 8; ++j) {
                        _Float16 h = (_Float16)av[j];
                        ah[j] = h;
                        al[j] = (_Float16)(av[j] - (float)h);
                    }
#pragma unroll
                    for (int nt = 0; nt < 8; ++nt) {
                        acc[mt][nt] = __builtin_amdgcn_mfma_f32_16x16x32_f16(ah, b[nt], acc[mt][nt], 0, 0, 0);
                        acc[mt][nt] = __builtin_amdgcn_mfma_f32_16x16x32_f16(al, b[nt], acc[mt][nt], 0, 0, 0);
                    }
                }
            }
        }
    }

    // epilogue: C/D layout col=lane&15, row=(lane>>4)*4+reg  [verified mapping]
#pragma unroll
    for (int mt = 0; mt < 2; ++mt) {
#pragma unroll
        for (int nt = 0; nt < 8; ++nt) {
            int col = nt * 16 + lr;
            float b = bias[col];
#pragma unroll
            for (int r = 0; r < 4; ++r) {
                int row = rowBase + mt * 16 + lk * 4 + r;
                if (row < NN) {
                    float v = acc[mt][nt][r] + b;
                    v = v > 0.f ? v : 0.f;
                    if (OF16)
                        ((_Float16*)out)[(size_t)row * 128 + col] = (_Float16)v;
                    else
                        ((float*)out)[(size_t)row * 128 + col] = v;
                }
            }
        }
    }
}

// ---------------- mean aggregation: wave per node, 4 rows per wave-load ----------------
// lane = g*16+f: group g handles edge slot j+g (and j+4+g, j+8+g, j+12+g),
// each lane loads half8 = features [f*8, f*8+8) of that row. 16B/lane, 4 rows
// per load instruction, 4 independent loads in flight per lane (4KB/wave).
__global__ __launch_bounds__(256) void k_agg(const _Float16* __restrict__ h,
                                             const int* __restrict__ rp,
                                             const int* __restrict__ ssrc,
                                             _Float16* __restrict__ out) {
    int wid = (int)((blockIdx.x * 256 + threadIdx.x) >> 6);
    int lane = threadIdx.x & 63;
    if (wid >= NN) return;
    int g = lane >> 4;
    int f = lane & 15;
    int s = __builtin_amdgcn_readfirstlane(rp[wid]);
    int e = __builtin_amdgcn_readfirstlane(rp[wid + 1]);
    int deg = e - s;

    float acc[8] = {0.f, 0.f, 0.f, 0.f, 0.f, 0.f, 0.f, 0.f};
    for (int j = s; j < e; j += 16) {
        int j0 = j + g, j1 = j + 4 + g, j2 = j + 8 + g, j3 = j + 12 + g;
        // clamped, branch-free loads (ssrc[s] is always valid inside the loop)
        int r0 = ssrc[j0 < e ? j0 : s];
        int r1 = ssrc[j1 < e ? j1 : s];
        int r2 = ssrc[j2 < e ? j2 : s];
        int r3 = ssrc[j3 < e ? j3 : s];
        half8 v0 = *(const half8*)(h + (size_t)r0 * 128 + f * 8);
        half8 v1 = *(const half8*)(h + (size_t)r1 * 128 + f * 8);
        half8 v2 = *(const half8*)(h + (size_t)r2 * 128 + f * 8);
        half8 v3 = *(const half8*)(h + (size_t)r3 * 128 + f * 8);
        float m0 = j0 < e ? 1.f : 0.f;
        float m1 = j1 < e ? 1.f : 0.f;
        float m2 = j2 < e ? 1.f : 0.f;
        float m3 = j3 < e ? 1.f : 0.f;
#pragma unroll
        for (int q = 0; q < 8; ++q) {
            acc[q] += m0 * (float)v0[q] + m1 * (float)v1[q]
                    + m2 * (float)v2[q] + m3 * (float)v3[q];
        }
    }
    // reduce across the 4 groups (lanes f, 16+f, 32+f, 48+f)
#pragma unroll
    for (int q = 0; q < 8; ++q) {
        acc[q] += __shfl_xor(acc[q], 16, 64);
        acc[q] += __shfl_xor(acc[q], 32, 64);
    }
    float inv = deg > 0 ? 1.0f / (float)deg : 0.f;
    if (g == 0) {
        half8 o;
#pragma unroll
        for (int q = 0; q < 8; ++q) o[q] = (_Float16)(acc[q] * inv);
        *(half8*)(out + (size_t)wid * 128 + f * 8) = o;
    }
}

// ---------------- launch ----------------
extern "C" void kernel_launch(void* const* d_in, const int* in_sizes, int n_in,
                              void* d_out, int out_size, void* d_ws, size_t ws_size,
                              hipStream_t stream) {
    const float* x = (const float*)d_in[0];
    const int* ei32 = (const int*)d_in[1];
    const long long* ei64 = (const long long*)d_in[1];
    const float* b1 = (const float*)d_in[3];
    const float* b2 = (const float*)d_in[5];
    const float* c1_bl = (const float*)d_in[7];
    const float* c2_bl = (const float*)d_in[10];

    char* ws = (char*)d_ws;
    const size_t H16 = (size_t)NN * 128 * 2;     // 25,600,000
    _Float16* hH = (_Float16*)ws;                // fp16 node table
    _Float16* aggH = (_Float16*)(ws + H16);      // fp16 mean / h2 table
    int* ssrc = (int*)(ws + 2 * H16);            // E ints
    int* rp = (int*)(ws + 2 * H16 + 6400000);    // N+1 (padded 400128)
    int* bufs = (int*)(ws + 2 * H16 + 6400000 + 400128);
    _Float16* whi = (_Float16*)(ws + 2 * H16 + 6400000 + 2 * 400128);
    int* flag = (int*)((char*)(whi + 6 * 16384));

    int* bcnt = bufs;                // NBUK
    int* bbase = bufs + 256;         // NBUK+1
    int* bcur = bufs + 512;          // NBUK
    unsigned* eb = (unsigned*)hH;    // E staged edges (hH written only later)

    k_detect<<<1, 256, 0, stream>>>(ei64, flag);
    hipMemsetAsync(bcnt, 0, NBUK * 4, stream);
    int pgrid = (EE + EPB - 1) / EPB;   // 196
    k_bhist<<<pgrid, 1024, 0, stream>>>(ei32, ei64, flag, bcnt);
    k_bscan<<<1, 256, 0, stream>>>(bcnt, bbase, bcur);
    k_part<<<pgrid, 1024, 0, stream>>>(ei32, ei64, flag, bcur, eb);
    k_bucket<<<NBUK, 1024, 0, stream>>>(eb, bbase, rp, ssrc);
    k_prepw<<<(6 * 16384 + 255) / 256, 256, 0, stream>>>(
        (const float*)d_in[2], (const float*)d_in[6], (const float*)d_in[8],
        (const float*)d_in[4], (const float*)d_in[9], (const float*)d_in[11], whi);

    dim3 g((NN + 127) / 128);
    int agrid = (NN + 3) / 4;
    // h1 = relu(x@W1.T+b1) -> fp16 hH
    k_gemm<false, false, true><<<g, 256, 0, stream>>>(
        x, whi + 0 * 16384, nullptr, nullptr, b1, hH);
    // conv1: mean-agg then dual GEMM, output fp16 in-place over aggH
    k_agg<<<agrid, 256, 0, stream>>>(hH, rp, ssrc, aggH);
    k_gemm<true, true, true><<<g, 256, 0, stream>>>(
        aggH, whi + 1 * 16384, hH, whi + 2 * 16384, c1_bl, aggH);
    // h3 = relu(h2@W2.T+b2) -> fp16 hH
    k_gemm<false, true, true><<<g, 256, 0, stream>>>(
        aggH, whi + 3 * 16384, nullptr, nullptr, b2, hH);
    // conv2
    k_agg<<<agrid, 256, 0, stream>>>(hH, rp, ssrc, aggH);
    k_gemm<true, true, false><<<g, 256, 0, stream>>>(
        aggH, whi + 4 * 16384, hH, whi + 5 * 16384, c2_bl, d_out);
}